// Round 8
// baseline (1742.027 us; speedup 1.0000x reference)
//
#include <hip/hip_runtime.h>
#include <stdint.h>

#define S_STEPS 512
#define OUT_N   10

typedef _Float16 half8   __attribute__((ext_vector_type(8)));
typedef float    f32x4   __attribute__((ext_vector_type(4)));
typedef uint16_t ushort8 __attribute__((ext_vector_type(8)));
typedef uint32_t u32x2   __attribute__((ext_vector_type(2)));
typedef uint32_t u32x4   __attribute__((ext_vector_type(4)));

// ---------------- layout detection for bool inputs ----------------
__global__ void detect_layout(const uint8_t* __restrict__ x, int* __restrict__ flag) {
    __shared__ int any;
    if (threadIdx.x == 0) any = 0;
    __syncthreads();
    int acc = 0;
    for (int i = 0; i < 64; ++i)
        acc |= x[(size_t)(threadIdx.x * 64 + i) * 4 + 1];
    if (acc) atomicOr(&any, 1);
    __syncthreads();
    if (threadIdx.x == 0) *flag = any ? 1 : 0;
}

// ---------------- pack x bits: one uint32 per (m,s) ----------------
__global__ void pack_x(const uint8_t* __restrict__ x, const int* __restrict__ flag,
                       uint32_t* __restrict__ xp) {
    const int stride = (*flag) ? 1 : 4;
    const int f = blockIdx.x * blockDim.x + threadIdx.x;
    const int val = x[(size_t)f * stride];
    const uint64_t mask = __ballot(val != 0);
    const int lane = threadIdx.x & 63;
    if ((lane & 31) == 0) {
        uint32_t w = (lane & 32) ? (uint32_t)(mask >> 32) : (uint32_t)mask;
        xp[f >> 5] = w;
    }
}

// ---------------- xm[s][blk][i]: 16-sample injection masks ----------------
// bit n of xm[s][blk][i] = x[blk*16+n][s][i]
__global__ void build_xm(const uint32_t* __restrict__ xp, uint16_t* __restrict__ xm) {
    const int tg = blockIdx.x * blockDim.x + threadIdx.x;   // 16384 = 512 s x 32 blk
    const int s = tg & 511, blk = tg >> 9;
    uint32_t wn[16];
#pragma unroll
    for (int nn = 0; nn < 16; ++nn) wn[nn] = xp[(size_t)(blk * 16 + nn) * 512 + s];
    uint16_t* row = xm + ((size_t)s * 32 + blk) * 32;
#pragma unroll
    for (int i = 0; i < 32; i += 2) {
        uint32_t a = 0, b = 0;
#pragma unroll
        for (int nn = 0; nn < 16; ++nn) {
            a |= ((wn[nn] >> i) & 1u) << nn;
            b |= ((wn[nn] >> (i + 1)) & 1u) << nn;
        }
        *(uint32_t*)&row[i] = a | (b << 16);
    }
}

// ---------------- A-fragments: Wp = W_res * primes as f16 MFMA tiles ----------
// frag[((tile*8+ks)*64+lane)]: 8 f16 = A[m = tile*16+(lane&15)][k = ks*32+quad*8+jj]
__global__ void build_Afrag(const uint8_t* __restrict__ wres, const int* __restrict__ primes,
                            const int* __restrict__ flag, uint32_t* __restrict__ Af) {
    const int tg = blockIdx.x * blockDim.x + threadIdx.x;   // 8192
    const int lane = tg & 63, ks = (tg >> 6) & 7, tile = tg >> 9;
    const int stride = (*flag) ? 1 : 4;
    const int m = tile * 16 + (lane & 15);
    const int k0 = ks * 32 + ((lane >> 4) & 3) * 8;
    uint32_t dw[4];
#pragma unroll
    for (int d = 0; d < 4; ++d) {
        uint32_t v = 0;
#pragma unroll
        for (int h = 0; h < 2; ++h) {
            const int k = k0 + 2 * d + h;
            uint16_t hb = 0;
            if (wres[(size_t)(m * 256 + k) * stride]) {
                union { _Float16 f; uint16_t u; } cv;
                cv.f = (_Float16)(float)primes[k];     // primes < 2048: exact in f16
                hb = cv.u;
            }
            v |= (uint32_t)hb << (16 * h);
        }
        dw[d] = v;
    }
    *(u32x4*)&Af[(size_t)tg * 4] = *(u32x4*)dw;
}

// ---------------- bit-pack the LUT: 256MB int32 -> 8MB bits ----------------
__device__ __forceinline__ uint32_t spread8(uint32_t x) {
    x = (x | (x << 12)) & 0x000F000Fu;
    x = (x | (x << 6))  & 0x03030303u;
    x = (x | (x << 3))  & 0x11111111u;
    return x;
}
__device__ __forceinline__ void pack_chunk(const int4 q, int lane, int chunk,
                                           uint32_t* __restrict__ lp32) {
    const uint64_t b0 = __ballot((q.x & 1) != 0);
    const uint64_t b1 = __ballot((q.y & 1) != 0);
    const uint64_t b2 = __ballot((q.z & 1) != 0);
    const uint64_t b3 = __ballot((q.w & 1) != 0);
    if (lane < 8) {
        const uint32_t B0 = (uint32_t)(b0 >> (8 * lane)) & 0xFF;
        const uint32_t B1 = (uint32_t)(b1 >> (8 * lane)) & 0xFF;
        const uint32_t B2 = (uint32_t)(b2 >> (8 * lane)) & 0xFF;
        const uint32_t B3 = (uint32_t)(b3 >> (8 * lane)) & 0xFF;
        const uint32_t w = spread8(B0) | (spread8(B1) << 1)
                         | (spread8(B2) << 2) | (spread8(B3) << 3);
        lp32[(size_t)chunk * 8 + lane] = w;
    }
}
__global__ void pack_lut(const int* __restrict__ lut, uint32_t* __restrict__ lp32) {
    const int lane = threadIdx.x & 63;
    const int gw = blockIdx.x * (blockDim.x >> 6) + (threadIdx.x >> 6);
    const int4* src = (const int4*)lut;
    for (int it = 0; it < 64; ++it) {
        const int c0 = gw * 128 + it * 2;
        const int4 q0 = src[(size_t)c0 * 64 + lane];
        const int4 q1 = src[(size_t)(c0 + 1) * 64 + lane];
        pack_chunk(q0, lane, c0, lp32);
        pack_chunk(q1, lane, c0 + 1, lp32);
    }
}

// ---------------- main: 16 samples/block, MFMA idx, one gather round/step ----
__global__ __launch_bounds__(256, 1) void reservoir_main(
    const uint16_t* __restrict__ xm, const uint32_t* __restrict__ Af,
    const uint64_t* __restrict__ lp, const int* __restrict__ input_nodes,
    const uint8_t* __restrict__ init_res, const int* __restrict__ flag,
    const float* __restrict__ rW, const float* __restrict__ rb,
    float* __restrict__ out)
{
    const int blk = blockIdx.x;
    const int t = threadIdx.x;
    const int w = t >> 6;           // wave 0..3: owns m-tiles 4w..4w+3
    const int l = t & 63;
    const int n = l & 15;           // sample column (MFMA B/C col = lane&15)
    const int quad = l >> 4;
    const int stride = (*flag) ? 1 : 4;

    __shared__ uint16_t m16[2][256];   // state masks, double-buffered

    // this lane writes node wnode's mask each step (ballot-transpose)
    const int wi = (l >> 2) & 3, wq = l & 3;
    const int wnode = w * 64 + quad * 16 + wq * 4 + wi;
    int slotL = -1;
#pragma unroll
    for (int k2 = 0; k2 < 32; ++k2) if (input_nodes[k2] == wnode) slotL = k2;

    // A fragments in registers, loop-invariant (4 tiles x 8 ksteps x 4 VGPR)
    half8 A[4][8];
#pragma unroll
    for (int tt = 0; tt < 4; ++tt)
#pragma unroll
        for (int ks = 0; ks < 8; ++ks)
            A[tt][ks] = *(const half8*)&Af[(size_t)(((w * 4 + tt) * 8 + ks) * 64 + l) * 4];

    // init m16[0] = init_res broadcast + s=0 injection
    {
        uint16_t base = init_res[(size_t)t * stride] ? 0xFFFFu : 0u;
        int sj = -1;
#pragma unroll
        for (int k2 = 0; k2 < 32; ++k2) if (input_nodes[k2] == t) sj = k2;
        if (sj >= 0) base = xm[(size_t)blk * 32 + sj];
        m16[0][t] = base;
    }
    __syncthreads();

    for (int s = 0; s < S_STEPS; ++s) {
        const int p = s & 1;
        // prefetch injection mask for step s+1 (joins the gather vmcnt batch)
        uint32_t xpre = 0;
        const int sp = (s + 1 < S_STEPS) ? s + 1 : S_STEPS - 1;
        if (slotL >= 0)
            asm volatile("global_load_ushort %0, %1, %2"
                         : "=v"(xpre)
                         : "v"((uint32_t)(((sp * 32 + blk) * 32 + slotL) * 2)), "s"(xm)
                         : "memory");

        // B fragments: bit n of m16 rows -> f16 0/1
        half8 B[8];
#pragma unroll
        for (int ks = 0; ks < 8; ++ks) {
            const int k0 = ks * 32 + quad * 8;
            const ushort8 mv = *(const ushort8*)&m16[p][k0];   // ds_read_b128, quad-bcast
            union { uint32_t u[4]; half8 h; } bb;
#pragma unroll
            for (int d = 0; d < 4; ++d) {
                const uint32_t lo = (mv[2 * d]     >> n) & 1u;
                const uint32_t hi = (mv[2 * d + 1] >> n) & 1u;
                bb.u[d] = (lo ? 0x00003C00u : 0u) | (hi ? 0x3C000000u : 0u);
            }
            B[ks] = bb.h;
        }

        // MFMA per tile; gathers issued per tile so early tiles' loads fly
        // during later tiles' MFMAs.  sc0: no L1 line allocation (4096
        // random 8B reads/block-step would thrash 64B lines through L1).
        u32x2 gw[4][4];
        uint32_t gl[4];
#pragma unroll
        for (int tt = 0; tt < 4; ++tt) {
            f32x4 acc = {0.f, 0.f, 0.f, 0.f};
#pragma unroll
            for (int ks = 0; ks < 8; ++ks)
                acc = __builtin_amdgcn_mfma_f32_16x16x32_f16(A[tt][ks], B[ks], acc, 0, 0, 0);
            gl[tt] = 0;
#pragma unroll
            for (int i = 0; i < 4; ++i) {
                const uint32_t idx = (uint32_t)acc[i];         // exact integer f32
                gl[tt] |= (idx & 63u) << (8 * i);
                const uint32_t off = (uint32_t)(((w * 4 + tt) * 16 + quad * 4 + i) * 32768u)
                                   + ((idx >> 3) & ~7u);
                asm volatile("global_load_dwordx2 %0, %1, %2 sc0"
                             : "=v"(gw[tt][i]) : "v"(off), "s"(lp) : "memory");
            }
        }
        asm volatile("s_waitcnt vmcnt(0)" ::: "memory");
        asm volatile("" : "+v"(xpre));
#pragma unroll
        for (int tt = 0; tt < 4; ++tt)
#pragma unroll
            for (int i = 0; i < 4; ++i) asm volatile("" : "+v"(gw[tt][i]));

        // extract bits -> 16 ballots = transpose to per-node 16-sample masks
        uint64_t sel[16];
#pragma unroll
        for (int tt = 0; tt < 4; ++tt)
#pragma unroll
            for (int i = 0; i < 4; ++i) {
                const uint32_t id6 = (gl[tt] >> (8 * i)) & 63u;
                const uint32_t hw2 = (id6 & 32) ? gw[tt][i].y : gw[tt][i].x;
                sel[tt * 4 + i] = __ballot(((hw2 >> (id6 & 31)) & 1u) != 0);
            }
        // constant-mask select tree: sel[0] = ballot[(l>>2)&15]
#pragma unroll
        for (int d = 0; d < 4; ++d) {
            const int mbit = 4 << d;
#pragma unroll
            for (int k2 = 0; k2 < (8 >> d); ++k2)
                sel[k2] = (l & mbit) ? sel[2 * k2 + 1] : sel[2 * k2];
        }
        uint16_t val = (uint16_t)(sel[0] >> (wq * 16));
        if (slotL >= 0 && s + 1 < S_STEPS) val = (uint16_t)xpre;  // inject s+1
        m16[1 - p][wnode] = val;
        __syncthreads();
    }

    // final state (pure lut output, no injection) is in m16[0]
    if (t < 16 * OUT_N) {
        const int nn = t / OUT_N;
        const int o  = t % OUT_N;
        float acc = 0.f;
        for (int j = 0; j < 256; ++j)
            if ((m16[0][j] >> nn) & 1) acc += rW[o * 256 + j];
        out[(size_t)(blk * 16 + nn) * OUT_N + o] = acc + rb[o];
    }
}

extern "C" void kernel_launch(void* const* d_in, const int* in_sizes, int n_in,
                              void* d_out, int out_size, void* d_ws, size_t ws_size,
                              hipStream_t stream) {
    const uint8_t* x        = (const uint8_t*)d_in[0];
    const int* input_nodes  = (const int*)d_in[1];
    const int* lut          = (const int*)d_in[2];
    const uint8_t* wres     = (const uint8_t*)d_in[3];
    const int* primes       = (const int*)d_in[4];
    const uint8_t* init_res = (const uint8_t*)d_in[5];
    const float* rW         = (const float*)d_in[6];
    const float* rb         = (const float*)d_in[7];
    float* out              = (float*)d_out;

    uint8_t* ws = (uint8_t*)d_ws;
    int*       flag = (int*)ws;                                  // @0
    uint32_t*  xp   = (uint32_t*)(ws + 4096);                    // 1 MB
    uint16_t*  xm   = (uint16_t*)(ws + 4096 + (1u << 20));       // 1 MB
    uint32_t*  Af   = (uint32_t*)(ws + 4096 + (2u << 20));       // 128 KB
    uint64_t*  lp   = (uint64_t*)(ws + 4096 + (2u << 20) + (128u << 10)); // 8 MB

    detect_layout<<<1, 256, 0, stream>>>(x, flag);
    pack_x<<<(512 * 512 * 32) / 256, 256, 0, stream>>>(x, flag, xp);
    build_xm<<<64, 256, 0, stream>>>(xp, xm);
    build_Afrag<<<32, 256, 0, stream>>>(wres, primes, flag, Af);
    pack_lut<<<512, 256, 0, stream>>>(lut, (uint32_t*)lp);
    reservoir_main<<<32, 256, 0, stream>>>(xm, Af, lp, input_nodes, init_res,
                                           flag, rW, rb, out);
}

// Round 9
// 1309.100 us; speedup vs baseline: 1.3307x; 1.3307x over previous
//
#include <hip/hip_runtime.h>
#include <stdint.h>

#define R_NODES 256
#define M_SAMP  512
#define S_STEPS 512
#define OUT_N   10
#define NPLANES 11          // primes < 2048

// ---------------- layout detection for bool inputs ----------------
// If bools were uploaded as int32, byte (4f+1) of every element is 0.
// If uploaded as uint8, ~half those bytes are 1.  flag=1 => uint8 layout.
__global__ void detect_layout(const uint8_t* __restrict__ x, int* __restrict__ flag) {
    __shared__ int any;
    if (threadIdx.x == 0) any = 0;
    __syncthreads();
    int acc = 0;
    for (int i = 0; i < 64; ++i)
        acc |= x[(size_t)(threadIdx.x * 64 + i) * 4 + 1];
    if (acc) atomicOr(&any, 1);
    __syncthreads();
    if (threadIdx.x == 0) *flag = any ? 1 : 0;
}

// ---------------- pack x bits: one uint32 per (m,s) ----------------
__global__ void pack_x(const uint8_t* __restrict__ x, const int* __restrict__ flag,
                       uint32_t* __restrict__ xp) {
    const int stride = (*flag) ? 1 : 4;
    const int f = blockIdx.x * blockDim.x + threadIdx.x;      // element idx, M*S*32 total
    const int val = x[(size_t)f * stride];
    const uint64_t mask = __ballot(val != 0);
    const int lane = threadIdx.x & 63;
    if ((lane & 31) == 0) {
        uint32_t w = (lane & 32) ? (uint32_t)(mask >> 32) : (uint32_t)mask;
        xp[f >> 5] = w;
    }
}

// ---------------- bit-plane masks Q[j][b][w] ----------------
// Qg[(b*4+w)*256 + j] = 64-bit mask over k in [64w,64w+64):
//   bit set iff W_res[j][k]=1 and bit b of primes[k] = 1.
// idx[j] = sum_b 2^b * popcount(r & Q[j][b])  -- exact integer arithmetic.
__global__ void build_Q(const uint8_t* __restrict__ wres, const int* __restrict__ primes,
                        const int* __restrict__ flag, uint64_t* __restrict__ Qg) {
    const int j = threadIdx.x;
    const int stride = (*flag) ? 1 : 4;
    uint64_t q[NPLANES][4];
#pragma unroll
    for (int b = 0; b < NPLANES; ++b)
        for (int w = 0; w < 4; ++w) q[b][w] = 0;
    for (int k = 0; k < 256; ++k) {
        if (wres[(size_t)(j * 256 + k) * stride]) {
            const uint32_t p = (uint32_t)primes[k];
#pragma unroll
            for (int b = 0; b < NPLANES; ++b)
                if ((p >> b) & 1u) q[b][k >> 6] |= 1ull << (k & 63);
        }
    }
#pragma unroll
    for (int b = 0; b < NPLANES; ++b)
#pragma unroll
        for (int w = 0; w < 4; ++w)
            Qg[(size_t)(b * 4 + w) * 256 + j] = q[b][w];
}

// ---------------- bit-pack the LUT: 256MB int32 -> 8MB bits ----------------
__device__ __forceinline__ uint32_t spread8(uint32_t x) {
    x = (x | (x << 12)) & 0x000F000Fu;
    x = (x | (x << 6))  & 0x03030303u;
    x = (x | (x << 3))  & 0x11111111u;
    return x;
}
__device__ __forceinline__ void pack_chunk(const int4 q, int lane, int chunk,
                                           uint32_t* __restrict__ lp32) {
    const uint64_t b0 = __ballot((q.x & 1) != 0);
    const uint64_t b1 = __ballot((q.y & 1) != 0);
    const uint64_t b2 = __ballot((q.z & 1) != 0);
    const uint64_t b3 = __ballot((q.w & 1) != 0);
    if (lane < 8) {
        const uint32_t B0 = (uint32_t)(b0 >> (8 * lane)) & 0xFF;
        const uint32_t B1 = (uint32_t)(b1 >> (8 * lane)) & 0xFF;
        const uint32_t B2 = (uint32_t)(b2 >> (8 * lane)) & 0xFF;
        const uint32_t B3 = (uint32_t)(b3 >> (8 * lane)) & 0xFF;
        const uint32_t w = spread8(B0) | (spread8(B1) << 1)
                         | (spread8(B2) << 2) | (spread8(B3) << 3);
        lp32[(size_t)chunk * 8 + lane] = w;
    }
}
__global__ void pack_lut(const int* __restrict__ lut, uint32_t* __restrict__ lp32) {
    const int lane = threadIdx.x & 63;
    const int gw = blockIdx.x * (blockDim.x >> 6) + (threadIdx.x >> 6); // global wave id, 2048
    const int4* src = (const int4*)lut;
    for (int it = 0; it < 64; ++it) {
        const int c0 = gw * 128 + it * 2;              // 262144 wave-chunks total
        const int4 q0 = src[(size_t)c0 * 64 + lane];
        const int4 q1 = src[(size_t)(c0 + 1) * 64 + lane];
        pack_chunk(q0, lane, c0, lp32);
        pack_chunk(q1, lane, c0 + 1, lp32);
    }
}

// ---------------- main reservoir scan: one block per sample ----------------
// Thread j owns node j. idx computed ENTIRELY in registers via 11 bit-plane
// weighted popcounts over the 256-bit state mask (Q resident in ~88 VGPRs,
// loaded once). Round-8 lesson: only ONE memory leg (the lut gather) may
// remain in the per-step chain; everything else must be VALU/LDS-cheap.
// Double-buffered lmask -> one barrier per step.
__global__ __launch_bounds__(256, 2) void reservoir_main(
    const uint32_t* __restrict__ xp, const uint64_t* __restrict__ Qg,
    const uint64_t* __restrict__ lp, const int* __restrict__ input_nodes,
    const uint8_t* __restrict__ init_res, const int* __restrict__ flag,
    const float* __restrict__ rW, const float* __restrict__ rb,
    float* __restrict__ out)
{
    const int m = blockIdx.x;
    const int j = threadIdx.x;
    const int wid = j >> 6;
    const int lane = j & 63;
    __shared__ uint64_t lmask[2][4];   // double-buffered -> 1 barrier per step
    __shared__ float lout[OUT_N];

    const int stride = (*flag) ? 1 : 4;
    int slot = -1;
#pragma unroll
    for (int i = 0; i < 32; ++i)
        if (input_nodes[i] == j) slot = i;

    // load this node's 44 plane-masks into registers (coalesced, one-time)
    uint64_t Q[NPLANES][4];
#pragma unroll
    for (int b = 0; b < NPLANES; ++b)
#pragma unroll
        for (int w = 0; w < 4; ++w)
            Q[b][w] = Qg[(size_t)(b * 4 + w) * 256 + j];

    int v = init_res[(size_t)j * stride] ? 1 : 0;
    const uint64_t* lrow = lp + (size_t)j * 4096;
    const uint32_t* xrow = xp + m * S_STEPS;

    for (int s = 0; s < S_STEPS; ++s) {
        const uint32_t xw = xrow[s];               // uniform -> scalar load
        if (slot >= 0) v = (xw >> slot) & 1;
        const uint64_t bal = __ballot(v != 0);
        const int p = s & 1;
        if (lane == 0) lmask[p][wid] = bal;
        __syncthreads();
        const uint64_t r0 = lmask[p][0], r1 = lmask[p][1];
        const uint64_t r2 = lmask[p][2], r3 = lmask[p][3];

        // idx = sum_b 2^b * popcount(r & Q[b])  (pure VALU, ~150 ops)
        uint32_t idx = 0;
#pragma unroll
        for (int b = 0; b < NPLANES; ++b) {
            const int cnt = __builtin_popcountll(r0 & Q[b][0])
                          + __builtin_popcountll(r1 & Q[b][1])
                          + __builtin_popcountll(r2 & Q[b][2])
                          + __builtin_popcountll(r3 & Q[b][3]);
            idx += (uint32_t)cnt << b;
        }

        // the single memory leg of the chain
        v = (int)((lrow[idx >> 6] >> (idx & 63)) & 1);
    }

    // readout: out[m][o] = b[o] + sum_j v_j * W[o][j]
    __syncthreads();
    if (j < OUT_N) lout[j] = 0.f;
    __syncthreads();
#pragma unroll
    for (int o = 0; o < OUT_N; ++o) {
        float contrib = v ? rW[o * R_NODES + j] : 0.f;
        for (int off = 32; off > 0; off >>= 1)
            contrib += __shfl_down(contrib, off, 64);
        if (lane == 0) atomicAdd(&lout[o], contrib);
    }
    __syncthreads();
    if (j < OUT_N) out[m * OUT_N + j] = lout[j] + rb[j];
}

extern "C" void kernel_launch(void* const* d_in, const int* in_sizes, int n_in,
                              void* d_out, int out_size, void* d_ws, size_t ws_size,
                              hipStream_t stream) {
    const uint8_t* x        = (const uint8_t*)d_in[0];   // bool [M,S,D,B]
    const int* input_nodes  = (const int*)d_in[1];       // int32 [32]
    const int* lut          = (const int*)d_in[2];       // int32 [256, 2^18]
    const uint8_t* wres     = (const uint8_t*)d_in[3];   // bool [256,256]
    const int* primes       = (const int*)d_in[4];       // int32 [256]
    const uint8_t* init_res = (const uint8_t*)d_in[5];   // bool [256]
    const float* rW         = (const float*)d_in[6];     // f32 [10,256]
    const float* rb         = (const float*)d_in[7];     // f32 [10]
    float* out              = (float*)d_out;             // f32 [512,10]

    uint8_t* ws = (uint8_t*)d_ws;
    int*      flag = (int*)ws;                                        // 4 B
    uint32_t* xp   = (uint32_t*)(ws + 4096);                          // 1 MB
    uint64_t* Qg   = (uint64_t*)(ws + 4096 + (1u << 20));             // 90 KB
    uint64_t* lp   = (uint64_t*)(ws + 4096 + (1u << 20) + (128u << 10)); // 8 MB

    detect_layout<<<1, 256, 0, stream>>>(x, flag);
    pack_x<<<(M_SAMP * S_STEPS * 32) / 256, 256, 0, stream>>>(x, flag, xp);
    build_Q<<<1, 256, 0, stream>>>(wres, primes, flag, Qg);
    pack_lut<<<512, 256, 0, stream>>>(lut, (uint32_t*)lp);
    reservoir_main<<<M_SAMP, 256, 0, stream>>>(xp, Qg, lp, input_nodes, init_res,
                                               flag, rW, rb, out);
}